// Round 14
// baseline (50.123 us; speedup 1.0000x reference)
//
#include <hip/hip_runtime.h>
#include <hip/hip_bf16.h>
#include <math.h>

#define T_DIM 8192
#define D_DIM 128
#define CHUNK 256
#define NCH   32          // chunks per batch
#define NAUG  160         // N_aug rows: 0..127 = A^T, 128 = a_prev, 129..159 = 0

typedef __attribute__((ext_vector_type(8))) __bf16 bf16x8;
typedef __attribute__((ext_vector_type(16))) float f32x16;
typedef __attribute__((ext_vector_type(4))) float f32x4;
typedef unsigned short us;

static __device__ __forceinline__ us f2bf(float f) {
    unsigned u = __builtin_bit_cast(unsigned, f);
    unsigned r = (u + 0x7FFFu + ((u >> 16) & 1u)) >> 16;
    return (us)r;
}
static __device__ __forceinline__ float gelu_tanh(float x) {
    const float c = 0.7978845608028654f; // sqrt(2/pi)
    float u = c * (x + 0.044715f * x * x * x);
    float e = __expf(2.0f * u);
    float th = 1.0f - 2.0f / (e + 1.0f);
    return 0.5f * x * (1.0f + th);
}
static __device__ __forceinline__ float softplus_f(float x) {
    return (x > 20.0f) ? x : log1pf(__expf(x));
}
// D-layout row for 32x32 MFMA accumulators
static __device__ __forceinline__ int rowD(int ri, int hi) {
    return (ri & 3) + 8 * (ri >> 2) + 4 * hi;
}

// ---------------------------------------------------------------------------
// K1 prep (EXACT R12): gelu + row-normalize. Writes:
//   on  bf16 [b][t][d]  (row-major, normalized)
//   onT bf16 [b][i][t]  normalized, transposed, sigma within 16-groups
//   vT  bf16 [b][d][t]  raw gelu, transposed, same sigma
// ---------------------------------------------------------------------------
__global__ __launch_bounds__(256) void prep_kernel(
    const float* __restrict__ x,
    us* __restrict__ on, us* __restrict__ onT, us* __restrict__ vT)
{
    __shared__ us vt[32 * 128];   // raw gelu
    __shared__ us nt[32 * 128];   // normalized
    const int blk = blockIdx.x;               // 512 blocks
    const int batch = blk >> 8;
    const int kb32 = (blk & 255) << 5;
    const int t = threadIdx.x;
    const int r = t >> 3;
    const int d0 = (t & 7) << 4;

    const size_t rowbase = ((size_t)batch * T_DIM + kb32 + r) * D_DIM;
    float g[16];
    #pragma unroll
    for (int i = 0; i < 16; i += 4) {
        f32x4 xv = *reinterpret_cast<const f32x4*>(x + rowbase + d0 + i);
        g[i+0] = gelu_tanh(xv[0]); g[i+1] = gelu_tanh(xv[1]);
        g[i+2] = gelu_tanh(xv[2]); g[i+3] = gelu_tanh(xv[3]);
    }
    float ss = 0.f;
    #pragma unroll
    for (int i = 0; i < 16; ++i) ss += g[i] * g[i];
    ss += __shfl_xor(ss, 1, 64); ss += __shfl_xor(ss, 2, 64); ss += __shfl_xor(ss, 4, 64);
    const float inv = 1.0f / fmaxf(sqrtf(ss), 1e-6f);

    unsigned pk[8], vp[8];
    #pragma unroll
    for (int i = 0; i < 8; ++i) {
        pk[i] = (unsigned)f2bf(g[2*i] * inv) | ((unsigned)f2bf(g[2*i+1] * inv) << 16);
        vp[i] = (unsigned)f2bf(g[2*i])       | ((unsigned)f2bf(g[2*i+1]) << 16);
    }
    uint4 oa = {pk[0],pk[1],pk[2],pk[3]}, ob = {pk[4],pk[5],pk[6],pk[7]};
    *reinterpret_cast<uint4*>(on + rowbase + d0)     = oa;
    *reinterpret_cast<uint4*>(on + rowbase + d0 + 8) = ob;
    uint4 va = {vp[0],vp[1],vp[2],vp[3]}, vb = {vp[4],vp[5],vp[6],vp[7]};
    *reinterpret_cast<uint4*>(&vt[r * 128 + d0])     = va;
    *reinterpret_cast<uint4*>(&vt[r * 128 + d0 + 8]) = vb;
    *reinterpret_cast<uint4*>(&nt[r * 128 + d0])     = oa;
    *reinterpret_cast<uint4*>(&nt[r * 128 + d0 + 8]) = ob;

    __syncthreads();

    // transpose-write with sigma within each 16-key half
    const int dd = t >> 1, h = (t & 1) * 16;
    us valsV[16], valsN[16];
    #pragma unroll
    for (int j = 0; j < 16; ++j) {
        const int sj = (j & 3) | ((j & 4) << 1) | ((j & 8) >> 1);
        valsV[j] = vt[(h + sj) * 128 + dd];
        valsN[j] = nt[(h + sj) * 128 + dd];
    }
    unsigned wv[8], wn[8];
    #pragma unroll
    for (int i = 0; i < 8; ++i) {
        wv[i] = (unsigned)valsV[2*i] | ((unsigned)valsV[2*i+1] << 16);
        wn[i] = (unsigned)valsN[2*i] | ((unsigned)valsN[2*i+1] << 16);
    }
    const size_t dbase = (size_t)batch * D_DIM * T_DIM + (size_t)dd * T_DIM + kb32 + h;
    uint4 wa = {wv[0],wv[1],wv[2],wv[3]}, wb = {wv[4],wv[5],wv[6],wv[7]};
    *reinterpret_cast<uint4*>(vT + dbase)     = wa;
    *reinterpret_cast<uint4*>(vT + dbase + 8) = wb;
    uint4 na = {wn[0],wn[1],wn[2],wn[3]}, nb = {wn[4],wn[5],wn[6],wn[7]};
    *reinterpret_cast<uint4*>(onT + dbase)     = na;
    *reinterpret_cast<uint4*>(onT + dbase + 8) = nb;
}

// ---------------------------------------------------------------------------
// K2 (EXACT R12): per-chunk outer products, i-split across 256 blocks.
// ---------------------------------------------------------------------------
__global__ __launch_bounds__(256) void chunk_outer_kernel(
    const us* __restrict__ onT, const us* __restrict__ vT,
    float* __restrict__ M, float* __restrict__ sum_out, float* __restrict__ sum_on)
{
    const int bx = blockIdx.x;            // 256 blocks
    const int b = bx & 1, c = (bx >> 1) & 31, p = bx >> 6;  // p = i-block 0..3
    const int s0 = c * CHUNK;
    const int tid = threadIdx.x;
    const int w = tid >> 6, lane = tid & 63, hi = lane >> 5, cc = lane & 31;

    const us* vb = vT  + (size_t)b * D_DIM * T_DIM;
    const us* ob = onT + (size_t)b * D_DIM * T_DIM;

    bf16x8 ones;
    #pragma unroll
    for (int j = 0; j < 8; ++j) ones[j] = (__bf16)1.0f;

    f32x16 acc, accS, accSon;
    #pragma unroll
    for (int ri = 0; ri < 16; ++ri) { acc[ri] = 0.f; accS[ri] = 0.f; accSon[ri] = 0.f; }

    #pragma unroll
    for (int dc = 0; dc < 16; ++dc) {
        bf16x8 af = *reinterpret_cast<const bf16x8*>(
            vb + (size_t)(32 * w + cc) * T_DIM + s0 + dc * 16 + hi * 8);
        bf16x8 bfr = *reinterpret_cast<const bf16x8*>(
            ob + (size_t)(p * 32 + cc) * T_DIM + s0 + dc * 16 + hi * 8);
        acc = __builtin_amdgcn_mfma_f32_32x32x16_bf16(af, bfr, acc, 0, 0, 0);
        if (p == 0)
            accS = __builtin_amdgcn_mfma_f32_32x32x16_bf16(af, ones, accS, 0, 0, 0);
        if (w == 0)
            accSon = __builtin_amdgcn_mfma_f32_32x32x16_bf16(bfr, ones, accSon, 0, 0, 0);
    }

    float* Mc = M + (size_t)(b * NCH + c) * 16384;
    #pragma unroll
    for (int ri = 0; ri < 16; ++ri) {
        const int qr = rowD(ri, hi);
        Mc[(32 * w + qr) * 128 + p * 32 + cc] = acc[ri];
    }
    if (p == 0 && cc == 0) {
        #pragma unroll
        for (int ri = 0; ri < 16; ++ri)
            sum_out[(size_t)(b * NCH + c) * 128 + 32 * w + rowD(ri, hi)] = accS[ri];
    }
    if (w == 0 && cc == 0) {
        #pragma unroll
        for (int ri = 0; ri < 16; ++ri)
            sum_on[(size_t)(b * NCH + c) * 128 + p * 32 + rowD(ri, hi)] = accSon[ri];
    }
}

// ---------------------------------------------------------------------------
// K3 (EXACT R12): exclusive prefix over chunks, fully unrolled.
// ---------------------------------------------------------------------------
__global__ __launch_bounds__(256) void scan_kernel(
    const float* __restrict__ M, const float* __restrict__ sum_out,
    const float* __restrict__ sum_on,
    us* __restrict__ Naug, float* __restrict__ S0p)
{
    const int id = blockIdx.x * 256 + threadIdx.x;   // 160 blocks -> 40960 ids
    const int b = id / 20480;
    const int rem = id % 20480;
    const int d = rem >> 7, i = rem & 127;
    if (d < 128) {
        float acc = 0.f;
        #pragma unroll
        for (int c = 0; c < NCH; ++c) {
            const size_t ch = (size_t)(b * NCH + c);
            Naug[ch * NAUG * 128 + d * 128 + i] = f2bf(acc);
            acc += M[ch * 16384 + d * 128 + i];
        }
    } else if (d == 128) {
        float aa = 0.f, ssum = 0.f;
        #pragma unroll
        for (int c = 0; c < NCH; ++c) {
            const size_t ch = (size_t)(b * NCH + c);
            Naug[ch * NAUG * 128 + 128 * 128 + i] = f2bf(aa);
            S0p[ch * 128 + i] = ssum;
            aa += sum_on[ch * 128 + i];
            ssum += sum_out[ch * 128 + i];
        }
    } else {
        #pragma unroll
        for (int c = 0; c < NCH; ++c)
            Naug[(size_t)(b * NCH + c) * NAUG * 128 + d * 128 + i] = 0;
    }
}

// ---------------------------------------------------------------------------
// K4: dt-SPLIT (this round's single change). One wave = 32 q-rows x 64
// d-columns (half h of the output). 1024 fully independent waves: each
// recomputes QK and den itself (+2 QK MFMAs/iter vs R12) but no partials,
// no sync, lower register pressure, 2x the TLP. Loop body structure is
// IDENTICAL to the passing R12 (fresh loads inside the loop, no buffers).
// ---------------------------------------------------------------------------
__global__ __launch_bounds__(64) void attn_lin_kernel(
    const float* __restrict__ x,
    const us* __restrict__ on, const us* __restrict__ vT,
    const us* __restrict__ Naug, const float* __restrict__ S0p,
    const float* __restrict__ lbr, const float* __restrict__ lar,
    float* __restrict__ out)
{
    __shared__ float lbuf[32];
    const int bx = blockIdx.x;             // 1024 blocks
    const int b = bx & 1;
    const int h = (bx >> 1) & 1;           // d-column half: cols [h*64, h*64+64)
    const int g = bx >> 2;                 // q-tile 0..255
    const int q0w = g << 5;
    const int c = g >> 3;
    const int c0 = c << 8;
    const int lane = threadIdx.x;
    const int hi = lane >> 5, cc = lane & 31;

    const float beta = fminf(softplus_f(lbr[0]), 5.0f) + 0.5f;
    const float gam = beta * 0.08838834764831843f;   // beta/sqrt(128)
    const float alpha = softplus_f(lar[0]);

    const us* onb = on + (size_t)b * T_DIM * D_DIM;
    const us* vTb = vT + (size_t)b * D_DIM * T_DIM;
    const us* Nc  = Naug + (size_t)(b * NCH + c) * NAUG * 128;

    // Q fragments, pre-scaled by gamma (dual-use as A-frag and B-frag)
    bf16x8 qf[8];
    #pragma unroll
    for (int dc = 0; dc < 8; ++dc) {
        bf16x8 a = *reinterpret_cast<const bf16x8*>(
            onb + (size_t)(q0w + cc) * D_DIM + dc * 16 + hi * 8);
        #pragma unroll
        for (int j = 0; j < 8; ++j) a[j] = (__bf16)((float)a[j] * gam);
        qf[dc] = a;
    }
    bf16x8 ones;
    #pragma unroll
    for (int j = 0; j < 8; ++j) ones[j] = (__bf16)1.0f;

    f32x16 acc[2], accden;
    #pragma unroll
    for (int dt = 0; dt < 2; ++dt)
        #pragma unroll
        for (int ri = 0; ri < 16; ++ri) acc[dt][ri] = 0.f;
    #pragma unroll
    for (int ri = 0; ri < 16; ++ri) accden[ri] = 0.f;

    // ---- prefix GEMM: acc += (gamma on) @ A_prev (this wave's 2 dt blocks);
    //      accden += (gamma on) . a_prev
    #pragma unroll
    for (int dc = 0; dc < 8; ++dc) {
        #pragma unroll
        for (int dt = 0; dt < 2; ++dt) {
            bf16x8 nf = *reinterpret_cast<const bf16x8*>(
                Nc + (h * 64 + dt * 32 + cc) * 128 + dc * 16 + hi * 8);
            acc[dt] = __builtin_amdgcn_mfma_f32_32x32x16_bf16(qf[dc], nf, acc[dt], 0, 0, 0);
        }
        bf16x8 nd = *reinterpret_cast<const bf16x8*>(
            Nc + (128 + cc) * 128 + dc * 16 + hi * 8);
        accden = __builtin_amdgcn_mfma_f32_32x32x16_bf16(qf[dc], nd, accden, 0, 0, 0);
    }

    // ---- intra-chunk causal part (R12 structure: fresh loads in-loop)
    for (int kb = c0; kb <= q0w; kb += 32) {
        f32x16 sv;
        #pragma unroll
        for (int ri = 0; ri < 16; ++ri) sv[ri] = 0.f;
        #pragma unroll
        for (int dc = 0; dc < 8; ++dc) {
            bf16x8 kf = *reinterpret_cast<const bf16x8*>(
                onb + (size_t)(kb + cc) * D_DIM + dc * 16 + hi * 8);
            sv = __builtin_amdgcn_mfma_f32_32x32x16_bf16(kf, qf[dc], sv, 0, 0, 0);
        }
        bf16x8 p00, p01;
        if (kb < q0w) {                    // fully-valid tile
            #pragma unroll
            for (int ri = 0; ri < 16; ++ri) {
                float p = 1.0f + sv[ri];
                if (ri < 8) p00[ri] = (__bf16)p; else p01[ri - 8] = (__bf16)p;
            }
        } else {                            // diagonal tile: causal mask
            const int q = q0w + cc;
            #pragma unroll
            for (int ri = 0; ri < 16; ++ri) {
                const int key = kb + rowD(ri, hi);
                float p = (key <= q) ? (1.0f + sv[ri]) : 0.f;
                if (ri < 8) p00[ri] = (__bf16)p; else p01[ri - 8] = (__bf16)p;
            }
        }
        accden = __builtin_amdgcn_mfma_f32_32x32x16_bf16(p00, ones, accden, 0, 0, 0);
        accden = __builtin_amdgcn_mfma_f32_32x32x16_bf16(p01, ones, accden, 0, 0, 0);
        #pragma unroll
        for (int dt = 0; dt < 2; ++dt) {
            const size_t rb = (size_t)(h * 64 + dt * 32 + cc) * T_DIM + kb + hi * 8;
            bf16x8 vf0 = *reinterpret_cast<const bf16x8*>(vTb + rb);
            bf16x8 vf1 = *reinterpret_cast<const bf16x8*>(vTb + rb + 16);
            acc[dt] = __builtin_amdgcn_mfma_f32_32x32x16_bf16(p00, vf0, acc[dt], 0, 0, 0);
            acc[dt] = __builtin_amdgcn_mfma_f32_32x32x16_bf16(p01, vf1, acc[dt], 0, 0, 0);
        }
    }

    // ---- den bounce (cc==0 lanes hold the real den) -> all lanes
    if (cc == 0) {
        #pragma unroll
        for (int ri = 0; ri < 16; ++ri)
            lbuf[rowD(ri, hi)] = (float)c0 + accden[ri];
    }
    float s0v[2];
    #pragma unroll
    for (int dt = 0; dt < 2; ++dt)
        s0v[dt] = S0p[(size_t)(b * NCH + c) * 128 + h * 64 + dt * 32 + cc];

    #pragma unroll
    for (int ri = 0; ri < 16; ++ri) {
        const int qr = rowD(ri, hi);
        const float invd = 1.0f / lbuf[qr];
        #pragma unroll
        for (int dt = 0; dt < 2; ++dt) {
            const float mu = (acc[dt][ri] + s0v[dt]) * invd;
            const size_t gi = ((size_t)b * T_DIM + q0w + qr) * D_DIM + h * 64 + dt * 32 + cc;
            const float gv = gelu_tanh(x[gi]);
            out[gi] = gv + alpha * (gv - mu);
        }
    }
}

extern "C" void kernel_launch(void* const* d_in, const int* in_sizes, int n_in,
                              void* d_out, int out_size, void* d_ws, size_t ws_size,
                              hipStream_t stream) {
    const float* x = (const float*)d_in[0];
    const float* lbr = (const float*)d_in[1];
    const float* lar = (const float*)d_in[2];
    float* out = (float*)d_out;

    us* on  = (us*)d_ws;                               // 4 MiB
    us* onT = on  + (size_t)2 * T_DIM * D_DIM;         // 4 MiB
    us* vT  = onT + (size_t)2 * T_DIM * D_DIM;         // 4 MiB
    float* M = (float*)(vT + (size_t)2 * T_DIM * D_DIM);      // 64*16384 f32 = 4 MiB
    float* sum_out = M + (size_t)64 * 16384;           // 64*128 f32
    float* sum_on  = sum_out + 64 * 128;
    float* S0p     = sum_on  + 64 * 128;
    us* Naug = (us*)(S0p + 64 * 128);                  // 64*160*128 bf16 = 2.5 MiB

    prep_kernel<<<dim3(512), dim3(256), 0, stream>>>(x, on, onT, vT);
    chunk_outer_kernel<<<dim3(256), dim3(256), 0, stream>>>(onT, vT, M, sum_out, sum_on);
    scan_kernel<<<dim3(160), dim3(256), 0, stream>>>(M, sum_out, sum_on, Naug, S0p);
    attn_lin_kernel<<<dim3(1024), dim3(64), 0, stream>>>(x, on, vT, Naug, S0p,
                                                         lbr, lar, out);
}